// Round 7
// baseline (538.441 us; speedup 1.0000x reference)
//
#include <hip/hip_runtime.h>

#define N_NODES 100000
#define N_ROWS_PAD 100032   // multiple of 64 for the MFMA kernel
#define N_EDGES 1600000
#define F_IN    128
#define HID     256
#define C_OUT   4

#define NB 391        // ceil(N_NODES/256) buckets / scan blocks
#define EPT 16        // edges per thread in k_bucket

#define GEMM_BLOCKS 256
#define NTASKS 6252   // N_ROWS_PAD / 16

typedef short short8v __attribute__((ext_vector_type(8)));
typedef unsigned short u16x8 __attribute__((ext_vector_type(8)));
typedef float f32x4 __attribute__((ext_vector_type(4)));

__device__ __forceinline__ ushort f2b(float f) {
    union { float f; unsigned u; } v; v.f = f;
    unsigned u = v.u;
    return (ushort)((u + 0x7FFFu + ((u >> 16) & 1u)) >> 16);   // RNE
}
__device__ __forceinline__ float b2f(ushort u) {
    union { unsigned u; float f; } v; v.u = ((unsigned)u) << 16; return v.f;
}

// async global->LDS, 16B per lane; lds dest = wave-uniform base + lane*16
__device__ __forceinline__ void gload16(const void* g, void* l) {
    __builtin_amdgcn_global_load_lds(
        (const __attribute__((address_space(1))) unsigned int*)g,
        (__attribute__((address_space(3))) unsigned int*)l, 16, 0, 0);
}

// ---------------------------------------------------------------------------
// K1: in-degree count
__global__ void k_count_deg(const int* __restrict__ ei, int* __restrict__ deg) {
    int e = blockIdx.x * 256 + threadIdx.x;
    if (e < N_EDGES) atomicAdd(&deg[ei[N_EDGES + e]], 1);
}

// K2a: per-block inclusive scan of deg -> per-element exclusive + block sums
__global__ void k_scan_blocks(const int* __restrict__ deg, int* __restrict__ excl,
                              int* __restrict__ bsum) {
    __shared__ int sh[256];
    int t = threadIdx.x;
    int i = blockIdx.x * 256 + t;
    int v = (i < N_NODES) ? deg[i] : 0;
    sh[t] = v;
    __syncthreads();
    #pragma unroll
    for (int off = 1; off < 256; off <<= 1) {
        int add = (t >= off) ? sh[t - off] : 0;
        __syncthreads();
        sh[t] += add;
        __syncthreads();
    }
    if (i < N_NODES) excl[i] = sh[t] - v;
    if (t == 255) bsum[blockIdx.x] = sh[255];
}

// K2b: scan of block sums (single block, 512 threads >= NB)
__global__ void k_scan_sums(const int* __restrict__ bsum, int* __restrict__ boff) {
    __shared__ int sh[512];
    int t = threadIdx.x;
    int v = (t < NB) ? bsum[t] : 0;
    sh[t] = v;
    __syncthreads();
    #pragma unroll
    for (int off = 1; off < 512; off <<= 1) {
        int add = (t >= off) ? sh[t - off] : 0;
        __syncthreads();
        sh[t] += add;
        __syncthreads();
    }
    boff[t] = sh[t] - v;
}

// K2c: rowptr / inv_deg / bucket cursors
__global__ void k_finalize(const int* __restrict__ deg, const int* __restrict__ excl,
                           const int* __restrict__ boff, int* __restrict__ rowptr,
                           int* __restrict__ bcur, float* __restrict__ inv_deg) {
    int i = blockIdx.x * 256 + threadIdx.x;
    if (i < N_NODES) {
        int r = excl[i] + boff[i >> 8];
        rowptr[i] = r;
        int d = deg[i];
        inv_deg[i] = (d > 0) ? 1.0f / (float)d : 0.0f;
    }
    if (i < 512) bcur[i] = boff[i];
    if (i == 0) rowptr[N_NODES] = N_EDGES;
}

// K3a: bucket edges by dst>>8. Block-local LDS histogram -> one global atomic
// per (block,bucket) reserves a contiguous run -> clustered int2 writes.
__global__ __launch_bounds__(256) void k_bucket(const int* __restrict__ ei,
                                                int* __restrict__ bcur,
                                                int2* __restrict__ ebuf) {
    __shared__ int hist[NB];
    __shared__ int sbase[NB];
    int t = threadIdx.x;
    for (int i = t; i < NB; i += 256) hist[i] = 0;
    __syncthreads();
    int src[EPT], dst[EPT], lofs[EPT];
    int base = blockIdx.x * (256 * EPT);
    #pragma unroll
    for (int i = 0; i < EPT; ++i) {
        int e = base + i * 256 + t;
        if (e < N_EDGES) {
            src[i] = ei[e];
            dst[i] = ei[N_EDGES + e];
            lofs[i] = atomicAdd(&hist[dst[i] >> 8], 1);
        } else dst[i] = -1;
    }
    __syncthreads();
    for (int i = t; i < NB; i += 256) {
        int h = hist[i];
        sbase[i] = h ? atomicAdd(&bcur[i], h) : 0;
    }
    __syncthreads();
    #pragma unroll
    for (int i = 0; i < EPT; ++i) {
        if (dst[i] >= 0)
            ebuf[sbase[dst[i] >> 8] + lofs[i]] = make_int2(src[i], dst[i]);
    }
}

// K3b: one block per bucket; LDS cursors; csr_src writes confined to this
// bucket's contiguous ~16KB CSR window -> full-line fills, no XCD sharing.
__global__ __launch_bounds__(256) void k_place(const int* __restrict__ boff,
                                               const int2* __restrict__ ebuf,
                                               const int* __restrict__ rowptr,
                                               int* __restrict__ csr_src) {
    __shared__ int lcur[256];
    int b = blockIdx.x, t = threadIdx.x;
    int node0 = b * 256;
    if (node0 + t < N_NODES) lcur[t] = rowptr[node0 + t];
    __syncthreads();
    int e1 = boff[b + 1];
    for (int i = boff[b] + t; i < e1; i += 256) {
        int2 ed = ebuf[i];
        int pos = atomicAdd(&lcur[ed.y & 255], 1);
        csr_src[pos] = ed.x;
    }
}

// K_xcast: bf16-cast x into ABF[row][128:256]  (3.2M threads, each 4 floats)
__global__ void k_xcast(const float* __restrict__ x, ushort* __restrict__ abf) {
    int t = blockIdx.x * 256 + threadIdx.x;        // [0, 3.2M)
    float4 xv = *(const float4*)(x + (size_t)t * 4);
    int row = t >> 5;
    int colq = (t & 31) * 4;
    ushort4 o; o.x = f2b(xv.x); o.y = f2b(xv.y); o.z = f2b(xv.z); o.w = f2b(xv.w);
    *(ushort4*)(abf + (size_t)row * 256 + 128 + colq) = o;
}

// K_wbf: WBF[col][k] bf16: [w1_l | w1_r] along k; also pack w2t[col][8]
__global__ void k_wbf(const float* __restrict__ w1l, const float* __restrict__ w1r,
                      const float* __restrict__ w2l, const float* __restrict__ w2r,
                      ushort* __restrict__ wbf, float* __restrict__ w2t) {
    int i = blockIdx.x * 256 + threadIdx.x;        // [0, 65536)
    int col = i >> 8, k = i & 255;
    float v = (k < 128) ? w1l[col * 128 + k] : w1r[col * 128 + (k - 128)];
    wbf[i] = f2b(v);
    if (i < 256) {
        #pragma unroll
        for (int c = 0; c < 4; ++c) {
            w2t[i * 8 + c]     = w2l[c * HID + i];
            w2t[i * 8 + 4 + c] = w2r[c * HID + i];
        }
    }
}

// K4: mean-aggregate bf16 x-rows over in-edges. One wave per node; 16 lanes
// per edge (uniform-address index load -> HW broadcast), 2-way unrolled ->
// 8 row-gathers in flight per wave.
__global__ void k_aggregate(const int* __restrict__ rowptr, const int* __restrict__ csr_src,
                            const float* __restrict__ inv_deg, ushort* __restrict__ abf) {
    int lane = threadIdx.x & 63;
    int v = blockIdx.x * 4 + (threadIdx.x >> 6);
    if (v >= N_NODES) return;
    int r0 = rowptr[v], r1 = rowptr[v + 1];
    int q = lane >> 4, li = lane & 15;
    float a0[8], a1[8];
    #pragma unroll
    for (int j = 0; j < 8; ++j) { a0[j] = 0.f; a1[j] = 0.f; }
    int e = r0 + q;
    for (; e + 4 < r1; e += 8) {
        int s0 = csr_src[e];
        int s1 = csr_src[e + 4];
        u16x8 u0 = *(const u16x8*)(abf + (size_t)s0 * 256 + 128 + li * 8);
        u16x8 u1 = *(const u16x8*)(abf + (size_t)s1 * 256 + 128 + li * 8);
        #pragma unroll
        for (int j = 0; j < 8; ++j) { a0[j] += b2f(u0[j]); a1[j] += b2f(u1[j]); }
    }
    if (e < r1) {
        int s0 = csr_src[e];
        u16x8 u0 = *(const u16x8*)(abf + (size_t)s0 * 256 + 128 + li * 8);
        #pragma unroll
        for (int j = 0; j < 8; ++j) a0[j] += b2f(u0[j]);
    }
    #pragma unroll
    for (int j = 0; j < 8; ++j) {
        float s = a0[j] + a1[j];
        s += __shfl_xor(s, 16);
        s += __shfl_xor(s, 32);
        a0[j] = s;
    }
    if (q == 0) {
        float id = inv_deg[v];
        u16x8 o;
        #pragma unroll
        for (int j = 0; j < 8; ++j) o[j] = f2b(a0[j] * id);
        *(u16x8*)(abf + (size_t)v * 256 + li * 8) = o;
    }
}

// K5: persistent MFMA GEMM  h = relu(ABF @ WBF^T + b1)  fused with layer-2
//     projections z = h @ w2l^T, r = h @ w2r^T  (h never materialized).
// 256 blocks x 512 threads (8 waves), 1 block/CU (LDS-limited). FULL B
// (128KB) staged to LDS once; afterwards ZERO barriers. Each wave owns
// 16-row tasks. __launch_bounds__(512, 1): rounds 5/6 used (512,2) which
// capped VGPR at 128 -> accumulator spill -> 700MB scratch traffic. The
// live set is ~160 VGPR and needs the 256-VGPR budget (2 waves/SIMD).
__global__ __launch_bounds__(512, 1) void k_mfma(
    const ushort* __restrict__ abf, const ushort* __restrict__ wbf,
    const float* __restrict__ b1, const float* __restrict__ w2t,
    float* __restrict__ zb, float* __restrict__ rb)
{
    __shared__ ushort bufB[16 * 8 * 512];   // 128KB: sub-buffer (n*8+kc) x 1KB

    int t = threadIdx.x;
    int w = t >> 6, l = t & 63;
    int lr = l & 15, lk = l >> 4;

    // stage all of B: wave w stages sub-buffers w*16 .. w*16+15
    #pragma unroll
    for (int j = 0; j < 16; ++j) {
        int sb = w * 16 + j;
        int n = sb >> 3, kc = sb & 7;
        gload16(wbf + (size_t)(n * 16 + lr) * 256 + kc * 32 + lk * 8,
                &bufB[sb * 512]);
    }
    __syncthreads();   // only barrier in the kernel

    int wid = blockIdx.x * 8 + w;
    int ps = (int)(((unsigned)wid * NTASKS) >> 11);        // balanced /2048
    int pe = (int)(((unsigned)(wid + 1) * NTASKS) >> 11);

    for (int p = ps; p < pe; ++p) {
        size_t r0 = (size_t)p * 16;
        // hoist this task's 8 A-frags (16B contiguous per lane, L3-hot)
        short8v af[8];
        const ushort* a0 = abf + (r0 + lr) * 256 + lk * 8;
        #pragma unroll
        for (int kc = 0; kc < 8; ++kc)
            af[kc] = *(const short8v*)(a0 + kc * 32);

        f32x4 acc[16] = {};
        #pragma unroll
        for (int kc = 0; kc < 8; ++kc) {
            #pragma unroll
            for (int n = 0; n < 16; ++n) {
                short8v bf = *(const short8v*)&bufB[(n * 8 + kc) * 512 + l * 8];
                acc[n] = __builtin_amdgcn_mfma_f32_16x16x32_bf16(af[kc], bf, acc[n], 0, 0, 0);
            }
        }

        // epilogue: bias+relu, layer-2 partials over this lane's 16 cols,
        // butterfly over the 16 lr-lanes, write z,r.
        float pz[4][8];
        #pragma unroll
        for (int q = 0; q < 4; ++q)
            #pragma unroll
            for (int c = 0; c < 8; ++c) pz[q][c] = 0.f;
        #pragma unroll
        for (int n = 0; n < 16; ++n) {
            int col = n * 16 + lr;
            float bias = b1[col];
            f32x4 wa = *(const f32x4*)(w2t + col * 8);
            f32x4 wb = *(const f32x4*)(w2t + col * 8 + 4);
            #pragma unroll
            for (int q = 0; q < 4; ++q) {
                float h = fmaxf(acc[n][q] + bias, 0.f);
                pz[q][0] += h * wa[0]; pz[q][1] += h * wa[1];
                pz[q][2] += h * wa[2]; pz[q][3] += h * wa[3];
                pz[q][4] += h * wb[0]; pz[q][5] += h * wb[1];
                pz[q][6] += h * wb[2]; pz[q][7] += h * wb[3];
            }
        }
        #pragma unroll
        for (int off = 1; off < 16; off <<= 1)
            #pragma unroll
            for (int q = 0; q < 4; ++q)
                #pragma unroll
                for (int c = 0; c < 8; ++c)
                    pz[q][c] += __shfl_xor(pz[q][c], off);
        if (lr == 0) {
            #pragma unroll
            for (int q = 0; q < 4; ++q) {
                size_t row = r0 + lk * 4 + q;   // C/D row=(l>>4)*4+reg
                if (row < N_NODES) {
                    *(float4*)(zb + row * 4) = make_float4(pz[q][0], pz[q][1], pz[q][2], pz[q][3]);
                    *(float4*)(rb + row * 4) = make_float4(pz[q][4], pz[q][5], pz[q][6], pz[q][7]);
                }
            }
        }
    }
}

// K6: aggregate z over in-edges, add bias + root term, log_softmax, write out.
__global__ void k_final(const float* __restrict__ zb, const float* __restrict__ rb,
                        const int* __restrict__ rowptr, const int* __restrict__ csr_src,
                        const float* __restrict__ inv_deg, const float* __restrict__ b2,
                        float* __restrict__ out) {
    int lane = threadIdx.x & 63;
    int v = blockIdx.x * 4 + (threadIdx.x >> 6);
    if (v >= N_NODES) return;
    int r0 = rowptr[v], r1 = rowptr[v + 1];
    float a0 = 0.f, a1 = 0.f, a2 = 0.f, a3 = 0.f;
    for (int idx = r0 + lane; idx < r1; idx += 64) {
        int s = csr_src[idx];
        float4 zv = *(const float4*)(zb + (size_t)s * 4);
        a0 += zv.x; a1 += zv.y; a2 += zv.z; a3 += zv.w;
    }
    #pragma unroll
    for (int off = 1; off < 64; off <<= 1) {
        a0 += __shfl_xor(a0, off);
        a1 += __shfl_xor(a1, off);
        a2 += __shfl_xor(a2, off);
        a3 += __shfl_xor(a3, off);
    }
    if (lane == 0) {
        float id = inv_deg[v];
        float4 rv = *(const float4*)(rb + (size_t)v * 4);
        float4 b2v = *(const float4*)b2;
        float h0 = a0 * id + b2v.x + rv.x;
        float h1 = a1 * id + b2v.y + rv.y;
        float h2 = a2 * id + b2v.z + rv.z;
        float h3 = a3 * id + b2v.w + rv.w;
        float mx = fmaxf(fmaxf(h0, h1), fmaxf(h2, h3));
        float s = expf(h0 - mx) + expf(h1 - mx) + expf(h2 - mx) + expf(h3 - mx);
        float lse = mx + logf(s);
        *(float4*)(out + (size_t)v * 4) = make_float4(h0 - lse, h1 - lse, h2 - lse, h3 - lse);
    }
}

// ---------------------------------------------------------------------------
extern "C" void kernel_launch(void* const* d_in, const int* in_sizes, int n_in,
                              void* d_out, int out_size, void* d_ws, size_t ws_size,
                              hipStream_t stream) {
    const float* x   = (const float*)d_in[0];
    const int*   ei  = (const int*)d_in[1];
    const float* w1l = (const float*)d_in[2];
    const float* w1r = (const float*)d_in[3];
    const float* b1  = (const float*)d_in[4];
    const float* w2l = (const float*)d_in[5];
    const float* w2r = (const float*)d_in[6];
    const float* b2  = (const float*)d_in[7];
    float* out = (float*)d_out;

    char* ws = (char*)d_ws;
    size_t off = 0;
    auto alloc = [&](size_t bytes) -> void* {
        void* p = ws + off;
        off = (off + bytes + 255) & ~(size_t)255;
        return p;
    };
    int* deg     = (int*)alloc(N_NODES * 4);
    int* excl    = (int*)alloc(N_NODES * 4);
    int* bsum    = (int*)alloc(512 * 4);
    int* boff    = (int*)alloc(512 * 4);
    int* rowptr  = (int*)alloc((N_NODES + 1) * 4);
    int* bcur    = (int*)alloc(512 * 4);
    int* csr_src = (int*)alloc((size_t)N_EDGES * 4);
    int2* ebuf   = (int2*)alloc((size_t)N_EDGES * 8);
    float* inv_deg = (float*)alloc(N_NODES * 4);
    ushort* abf  = (ushort*)alloc((size_t)N_ROWS_PAD * 256 * 2);  // [agg | x] bf16
    ushort* wbf  = (ushort*)alloc((size_t)256 * 256 * 2);         // [w1l | w1r] bf16
    float* w2t   = (float*)alloc(256 * 8 * 4);                    // [col][z0..3 r0..3]
    float* zb    = (float*)alloc((size_t)N_NODES * 4 * 4);
    float* rb    = (float*)alloc((size_t)N_NODES * 4 * 4);

    hipMemsetAsync(deg, 0, N_NODES * 4, stream);

    const int EB = (N_EDGES + 255) / 256;   // 6250
    k_count_deg<<<EB, 256, 0, stream>>>(ei, deg);
    k_scan_blocks<<<NB, 256, 0, stream>>>(deg, excl, bsum);
    k_scan_sums<<<1, 512, 0, stream>>>(bsum, boff);
    k_finalize<<<NB, 256, 0, stream>>>(deg, excl, boff, rowptr, bcur, inv_deg);
    k_bucket<<<(N_EDGES + 256 * EPT - 1) / (256 * EPT), 256, 0, stream>>>(ei, bcur, ebuf);
    k_place<<<NB, 256, 0, stream>>>(boff, ebuf, rowptr, csr_src);
    k_wbf<<<256, 256, 0, stream>>>(w1l, w1r, w2l, w2r, wbf, w2t);
    k_xcast<<<12500, 256, 0, stream>>>(x, abf);
    k_aggregate<<<(N_NODES + 3) / 4, 256, 0, stream>>>(rowptr, csr_src, inv_deg, abf);
    k_mfma<<<GEMM_BLOCKS, 512, 0, stream>>>(abf, wbf, b1, w2t, zb, rb);
    k_final<<<(N_NODES + 3) / 4, 256, 0, stream>>>(zb, rb, rowptr, csr_src, inv_deg, b2, out);
}

// Round 8
// 437.311 us; speedup vs baseline: 1.2313x; 1.2313x over previous
//
#include <hip/hip_runtime.h>

#define N_NODES 100000
#define N_ROWS_PAD 100032   // multiple of 64 for the MFMA kernel
#define N_EDGES 1600000
#define F_IN    128
#define HID     256
#define C_OUT   4

#define NB 391        // ceil(N_NODES/256) buckets / scan blocks
#define EPT 16        // edges per thread in k_bucket

#define GEMM_BLOCKS 256
#define NTASKS 6252   // N_ROWS_PAD / 16

typedef short short8v __attribute__((ext_vector_type(8)));
typedef unsigned short u16x8 __attribute__((ext_vector_type(8)));
typedef float f32x4 __attribute__((ext_vector_type(4)));

__device__ __forceinline__ ushort f2b(float f) {
    union { float f; unsigned u; } v; v.f = f;
    unsigned u = v.u;
    return (ushort)((u + 0x7FFFu + ((u >> 16) & 1u)) >> 16);   // RNE
}
__device__ __forceinline__ float b2f(ushort u) {
    union { unsigned u; float f; } v; v.u = ((unsigned)u) << 16; return v.f;
}

// async global->LDS, 16B per lane; lds dest = wave-uniform base + lane*16
__device__ __forceinline__ void gload16(const void* g, void* l) {
    __builtin_amdgcn_global_load_lds(
        (const __attribute__((address_space(1))) unsigned int*)g,
        (__attribute__((address_space(3))) unsigned int*)l, 16, 0, 0);
}

// ---------------------------------------------------------------------------
// K1: in-degree count
__global__ void k_count_deg(const int* __restrict__ ei, int* __restrict__ deg) {
    int e = blockIdx.x * 256 + threadIdx.x;
    if (e < N_EDGES) atomicAdd(&deg[ei[N_EDGES + e]], 1);
}

// K2a: per-block inclusive scan of deg -> per-element exclusive + block sums
__global__ void k_scan_blocks(const int* __restrict__ deg, int* __restrict__ excl,
                              int* __restrict__ bsum) {
    __shared__ int sh[256];
    int t = threadIdx.x;
    int i = blockIdx.x * 256 + t;
    int v = (i < N_NODES) ? deg[i] : 0;
    sh[t] = v;
    __syncthreads();
    #pragma unroll
    for (int off = 1; off < 256; off <<= 1) {
        int add = (t >= off) ? sh[t - off] : 0;
        __syncthreads();
        sh[t] += add;
        __syncthreads();
    }
    if (i < N_NODES) excl[i] = sh[t] - v;
    if (t == 255) bsum[blockIdx.x] = sh[255];
}

// K2b: scan of block sums (single block, 512 threads >= NB)
__global__ void k_scan_sums(const int* __restrict__ bsum, int* __restrict__ boff) {
    __shared__ int sh[512];
    int t = threadIdx.x;
    int v = (t < NB) ? bsum[t] : 0;
    sh[t] = v;
    __syncthreads();
    #pragma unroll
    for (int off = 1; off < 512; off <<= 1) {
        int add = (t >= off) ? sh[t - off] : 0;
        __syncthreads();
        sh[t] += add;
        __syncthreads();
    }
    boff[t] = sh[t] - v;
}

// K2c: rowptr / inv_deg / bucket cursors
__global__ void k_finalize(const int* __restrict__ deg, const int* __restrict__ excl,
                           const int* __restrict__ boff, int* __restrict__ rowptr,
                           int* __restrict__ bcur, float* __restrict__ inv_deg) {
    int i = blockIdx.x * 256 + threadIdx.x;
    if (i < N_NODES) {
        int r = excl[i] + boff[i >> 8];
        rowptr[i] = r;
        int d = deg[i];
        inv_deg[i] = (d > 0) ? 1.0f / (float)d : 0.0f;
    }
    if (i < 512) bcur[i] = boff[i];
    if (i == 0) rowptr[N_NODES] = N_EDGES;
}

// K3a: bucket edges by dst>>8. Block-local LDS histogram -> one global atomic
// per (block,bucket) reserves a contiguous run -> clustered int2 writes.
__global__ __launch_bounds__(256) void k_bucket(const int* __restrict__ ei,
                                                int* __restrict__ bcur,
                                                int2* __restrict__ ebuf) {
    __shared__ int hist[NB];
    __shared__ int sbase[NB];
    int t = threadIdx.x;
    for (int i = t; i < NB; i += 256) hist[i] = 0;
    __syncthreads();
    int src[EPT], dst[EPT], lofs[EPT];
    int base = blockIdx.x * (256 * EPT);
    #pragma unroll
    for (int i = 0; i < EPT; ++i) {
        int e = base + i * 256 + t;
        if (e < N_EDGES) {
            src[i] = ei[e];
            dst[i] = ei[N_EDGES + e];
            lofs[i] = atomicAdd(&hist[dst[i] >> 8], 1);
        } else dst[i] = -1;
    }
    __syncthreads();
    for (int i = t; i < NB; i += 256) {
        int h = hist[i];
        sbase[i] = h ? atomicAdd(&bcur[i], h) : 0;
    }
    __syncthreads();
    #pragma unroll
    for (int i = 0; i < EPT; ++i) {
        if (dst[i] >= 0)
            ebuf[sbase[dst[i] >> 8] + lofs[i]] = make_int2(src[i], dst[i]);
    }
}

// K3b: one block per bucket; LDS cursors; csr_src writes confined to this
// bucket's contiguous ~16KB CSR window -> full-line fills, no XCD sharing.
__global__ __launch_bounds__(256) void k_place(const int* __restrict__ boff,
                                               const int2* __restrict__ ebuf,
                                               const int* __restrict__ rowptr,
                                               int* __restrict__ csr_src) {
    __shared__ int lcur[256];
    int b = blockIdx.x, t = threadIdx.x;
    int node0 = b * 256;
    if (node0 + t < N_NODES) lcur[t] = rowptr[node0 + t];
    __syncthreads();
    int e1 = boff[b + 1];
    for (int i = boff[b] + t; i < e1; i += 256) {
        int2 ed = ebuf[i];
        int pos = atomicAdd(&lcur[ed.y & 255], 1);
        csr_src[pos] = ed.x;
    }
}

// K_xcast: bf16-cast x into ABF[row][128:256]  (3.2M threads, each 4 floats)
__global__ void k_xcast(const float* __restrict__ x, ushort* __restrict__ abf) {
    int t = blockIdx.x * 256 + threadIdx.x;        // [0, 3.2M)
    float4 xv = *(const float4*)(x + (size_t)t * 4);
    int row = t >> 5;
    int colq = (t & 31) * 4;
    ushort4 o; o.x = f2b(xv.x); o.y = f2b(xv.y); o.z = f2b(xv.z); o.w = f2b(xv.w);
    *(ushort4*)(abf + (size_t)row * 256 + 128 + colq) = o;
}

// K_wbf: WBF[col][k] bf16: [w1_l | w1_r] along k; also pack w2t[col][8]
__global__ void k_wbf(const float* __restrict__ w1l, const float* __restrict__ w1r,
                      const float* __restrict__ w2l, const float* __restrict__ w2r,
                      ushort* __restrict__ wbf, float* __restrict__ w2t) {
    int i = blockIdx.x * 256 + threadIdx.x;        // [0, 65536)
    int col = i >> 8, k = i & 255;
    float v = (k < 128) ? w1l[col * 128 + k] : w1r[col * 128 + (k - 128)];
    wbf[i] = f2b(v);
    if (i < 256) {
        #pragma unroll
        for (int c = 0; c < 4; ++c) {
            w2t[i * 8 + c]     = w2l[c * HID + i];
            w2t[i * 8 + 4 + c] = w2r[c * HID + i];
        }
    }
}

// K4: mean-aggregate bf16 x-rows over in-edges. One wave per node; 16 lanes
// per edge (uniform-address index load -> HW broadcast), 2-way unrolled ->
// 8 row-gathers in flight per wave.
__global__ void k_aggregate(const int* __restrict__ rowptr, const int* __restrict__ csr_src,
                            const float* __restrict__ inv_deg, ushort* __restrict__ abf) {
    int lane = threadIdx.x & 63;
    int v = blockIdx.x * 4 + (threadIdx.x >> 6);
    if (v >= N_NODES) return;
    int r0 = rowptr[v], r1 = rowptr[v + 1];
    int q = lane >> 4, li = lane & 15;
    float a0[8], a1[8];
    #pragma unroll
    for (int j = 0; j < 8; ++j) { a0[j] = 0.f; a1[j] = 0.f; }
    int e = r0 + q;
    for (; e + 4 < r1; e += 8) {
        int s0 = csr_src[e];
        int s1 = csr_src[e + 4];
        u16x8 u0 = *(const u16x8*)(abf + (size_t)s0 * 256 + 128 + li * 8);
        u16x8 u1 = *(const u16x8*)(abf + (size_t)s1 * 256 + 128 + li * 8);
        #pragma unroll
        for (int j = 0; j < 8; ++j) { a0[j] += b2f(u0[j]); a1[j] += b2f(u1[j]); }
    }
    if (e < r1) {
        int s0 = csr_src[e];
        u16x8 u0 = *(const u16x8*)(abf + (size_t)s0 * 256 + 128 + li * 8);
        #pragma unroll
        for (int j = 0; j < 8; ++j) a0[j] += b2f(u0[j]);
    }
    #pragma unroll
    for (int j = 0; j < 8; ++j) {
        float s = a0[j] + a1[j];
        s += __shfl_xor(s, 16);
        s += __shfl_xor(s, 32);
        a0[j] = s;
    }
    if (q == 0) {
        float id = inv_deg[v];
        u16x8 o;
        #pragma unroll
        for (int j = 0; j < 8; ++j) o[j] = f2b(a0[j] * id);
        *(u16x8*)(abf + (size_t)v * 256 + li * 8) = o;
    }
}

// K5: persistent MFMA GEMM  h = relu(ABF @ WBF^T + b1)  fused with layer-2
//     projections z = h @ w2l^T, r = h @ w2r^T  (h never materialized).
// 256 blocks x 256 THREADS (4 waves = 1 wave/SIMD), 1 block/CU (128KB LDS).
// FULL B staged to LDS once; afterwards ZERO barriers; each wave owns 16-row
// tasks. WHY 256 threads: rounds 5-7 used 512-thread workgroups -> hipcc
// caps VGPR at 128 for 8-wave co-residency (launch_bounds(512,1) did NOT
// lift it) -> accumulators spilled to scratch -> ~650MB HBM traffic, 324us.
// Round 3 proved this exact register pattern (acc[16] f32x4 + af[8] + pz)
// compiles to 132 VGPR spill-free at 256-thread workgroups.
__global__ __launch_bounds__(256, 1) void k_mfma(
    const ushort* __restrict__ abf, const ushort* __restrict__ wbf,
    const float* __restrict__ b1, const float* __restrict__ w2t,
    float* __restrict__ zb, float* __restrict__ rb)
{
    __shared__ ushort bufB[16 * 8 * 512];   // 128KB: sub-buffer (n*8+kc) x 1KB

    int t = threadIdx.x;
    int w = t >> 6, l = t & 63;
    int lr = l & 15, lk = l >> 4;

    // stage all of B: wave w stages sub-buffers w*32 .. w*32+31
    #pragma unroll
    for (int j = 0; j < 32; ++j) {
        int sb = w * 32 + j;
        int n = sb >> 3, kc = sb & 7;
        gload16(wbf + (size_t)(n * 16 + lr) * 256 + kc * 32 + lk * 8,
                &bufB[sb * 512]);
    }
    __syncthreads();   // only barrier in the kernel

    int wid = blockIdx.x * 4 + w;                          // [0, 1024)
    int ps = (int)(((unsigned)wid * NTASKS) >> 10);        // balanced /1024
    int pe = (int)(((unsigned)(wid + 1) * NTASKS) >> 10);

    for (int p = ps; p < pe; ++p) {
        size_t r0 = (size_t)p * 16;
        // hoist this task's 8 A-frags (16B contiguous per lane, L3-hot)
        short8v af[8];
        const ushort* a0 = abf + (r0 + lr) * 256 + lk * 8;
        #pragma unroll
        for (int kc = 0; kc < 8; ++kc)
            af[kc] = *(const short8v*)(a0 + kc * 32);

        f32x4 acc[16] = {};
        #pragma unroll
        for (int kc = 0; kc < 8; ++kc) {
            #pragma unroll
            for (int n = 0; n < 16; ++n) {
                short8v bf = *(const short8v*)&bufB[(n * 8 + kc) * 512 + l * 8];
                acc[n] = __builtin_amdgcn_mfma_f32_16x16x32_bf16(af[kc], bf, acc[n], 0, 0, 0);
            }
        }

        // epilogue: bias+relu, layer-2 partials over this lane's 16 cols,
        // butterfly over the 16 lr-lanes, write z,r.
        float pz[4][8];
        #pragma unroll
        for (int q = 0; q < 4; ++q)
            #pragma unroll
            for (int c = 0; c < 8; ++c) pz[q][c] = 0.f;
        #pragma unroll
        for (int n = 0; n < 16; ++n) {
            int col = n * 16 + lr;
            float bias = b1[col];
            f32x4 wa = *(const f32x4*)(w2t + col * 8);
            f32x4 wb = *(const f32x4*)(w2t + col * 8 + 4);
            #pragma unroll
            for (int q = 0; q < 4; ++q) {
                float h = fmaxf(acc[n][q] + bias, 0.f);
                pz[q][0] += h * wa[0]; pz[q][1] += h * wa[1];
                pz[q][2] += h * wa[2]; pz[q][3] += h * wa[3];
                pz[q][4] += h * wb[0]; pz[q][5] += h * wb[1];
                pz[q][6] += h * wb[2]; pz[q][7] += h * wb[3];
            }
        }
        #pragma unroll
        for (int off = 1; off < 16; off <<= 1)
            #pragma unroll
            for (int q = 0; q < 4; ++q)
                #pragma unroll
                for (int c = 0; c < 8; ++c)
                    pz[q][c] += __shfl_xor(pz[q][c], off);
        if (lr == 0) {
            #pragma unroll
            for (int q = 0; q < 4; ++q) {
                size_t row = r0 + lk * 4 + q;   // C/D row=(l>>4)*4+reg
                if (row < N_NODES) {
                    *(float4*)(zb + row * 4) = make_float4(pz[q][0], pz[q][1], pz[q][2], pz[q][3]);
                    *(float4*)(rb + row * 4) = make_float4(pz[q][4], pz[q][5], pz[q][6], pz[q][7]);
                }
            }
        }
    }
}

// K6: aggregate z over in-edges, add bias + root term, log_softmax, write out.
__global__ void k_final(const float* __restrict__ zb, const float* __restrict__ rb,
                        const int* __restrict__ rowptr, const int* __restrict__ csr_src,
                        const float* __restrict__ inv_deg, const float* __restrict__ b2,
                        float* __restrict__ out) {
    int lane = threadIdx.x & 63;
    int v = blockIdx.x * 4 + (threadIdx.x >> 6);
    if (v >= N_NODES) return;
    int r0 = rowptr[v], r1 = rowptr[v + 1];
    float a0 = 0.f, a1 = 0.f, a2 = 0.f, a3 = 0.f;
    for (int idx = r0 + lane; idx < r1; idx += 64) {
        int s = csr_src[idx];
        float4 zv = *(const float4*)(zb + (size_t)s * 4);
        a0 += zv.x; a1 += zv.y; a2 += zv.z; a3 += zv.w;
    }
    #pragma unroll
    for (int off = 1; off < 64; off <<= 1) {
        a0 += __shfl_xor(a0, off);
        a1 += __shfl_xor(a1, off);
        a2 += __shfl_xor(a2, off);
        a3 += __shfl_xor(a3, off);
    }
    if (lane == 0) {
        float id = inv_deg[v];
        float4 rv = *(const float4*)(rb + (size_t)v * 4);
        float4 b2v = *(const float4*)b2;
        float h0 = a0 * id + b2v.x + rv.x;
        float h1 = a1 * id + b2v.y + rv.y;
        float h2 = a2 * id + b2v.z + rv.z;
        float h3 = a3 * id + b2v.w + rv.w;
        float mx = fmaxf(fmaxf(h0, h1), fmaxf(h2, h3));
        float s = expf(h0 - mx) + expf(h1 - mx) + expf(h2 - mx) + expf(h3 - mx);
        float lse = mx + logf(s);
        *(float4*)(out + (size_t)v * 4) = make_float4(h0 - lse, h1 - lse, h2 - lse, h3 - lse);
    }
}

// ---------------------------------------------------------------------------
extern "C" void kernel_launch(void* const* d_in, const int* in_sizes, int n_in,
                              void* d_out, int out_size, void* d_ws, size_t ws_size,
                              hipStream_t stream) {
    const float* x   = (const float*)d_in[0];
    const int*   ei  = (const int*)d_in[1];
    const float* w1l = (const float*)d_in[2];
    const float* w1r = (const float*)d_in[3];
    const float* b1  = (const float*)d_in[4];
    const float* w2l = (const float*)d_in[5];
    const float* w2r = (const float*)d_in[6];
    const float* b2  = (const float*)d_in[7];
    float* out = (float*)d_out;

    char* ws = (char*)d_ws;
    size_t off = 0;
    auto alloc = [&](size_t bytes) -> void* {
        void* p = ws + off;
        off = (off + bytes + 255) & ~(size_t)255;
        return p;
    };
    int* deg     = (int*)alloc(N_NODES * 4);
    int* excl    = (int*)alloc(N_NODES * 4);
    int* bsum    = (int*)alloc(512 * 4);
    int* boff    = (int*)alloc(512 * 4);
    int* rowptr  = (int*)alloc((N_NODES + 1) * 4);
    int* bcur    = (int*)alloc(512 * 4);
    int* csr_src = (int*)alloc((size_t)N_EDGES * 4);
    int2* ebuf   = (int2*)alloc((size_t)N_EDGES * 8);
    float* inv_deg = (float*)alloc(N_NODES * 4);
    ushort* abf  = (ushort*)alloc((size_t)N_ROWS_PAD * 256 * 2);  // [agg | x] bf16
    ushort* wbf  = (ushort*)alloc((size_t)256 * 256 * 2);         // [w1l | w1r] bf16
    float* w2t   = (float*)alloc(256 * 8 * 4);                    // [col][z0..3 r0..3]
    float* zb    = (float*)alloc((size_t)N_NODES * 4 * 4);
    float* rb    = (float*)alloc((size_t)N_NODES * 4 * 4);

    hipMemsetAsync(deg, 0, N_NODES * 4, stream);

    const int EB = (N_EDGES + 255) / 256;   // 6250
    k_count_deg<<<EB, 256, 0, stream>>>(ei, deg);
    k_scan_blocks<<<NB, 256, 0, stream>>>(deg, excl, bsum);
    k_scan_sums<<<1, 512, 0, stream>>>(bsum, boff);
    k_finalize<<<NB, 256, 0, stream>>>(deg, excl, boff, rowptr, bcur, inv_deg);
    k_bucket<<<(N_EDGES + 256 * EPT - 1) / (256 * EPT), 256, 0, stream>>>(ei, bcur, ebuf);
    k_place<<<NB, 256, 0, stream>>>(boff, ebuf, rowptr, csr_src);
    k_wbf<<<256, 256, 0, stream>>>(w1l, w1r, w2l, w2r, wbf, w2t);
    k_xcast<<<12500, 256, 0, stream>>>(x, abf);
    k_aggregate<<<(N_NODES + 3) / 4, 256, 0, stream>>>(rowptr, csr_src, inv_deg, abf);
    k_mfma<<<GEMM_BLOCKS, 256, 0, stream>>>(abf, wbf, b1, w2t, zb, rb);
    k_final<<<(N_NODES + 3) / 4, 256, 0, stream>>>(zb, rb, rowptr, csr_src, inv_deg, b2, out);
}

// Round 9
// 263.818 us; speedup vs baseline: 2.0410x; 1.6576x over previous
//
#include <hip/hip_runtime.h>

#define N_NODES 100000
#define N_ROWS_PAD 100032   // multiple of 64 for the MFMA kernel
#define N_EDGES 1600000
#define F_IN    128
#define HID     256
#define C_OUT   4

#define NB 391        // ceil(N_NODES/256) buckets / scan blocks
#define EPT 16        // edges per thread in k_bucket

#define GEMM_BLOCKS 256
#define NTASKS 6252   // N_ROWS_PAD / 16

typedef short short8v __attribute__((ext_vector_type(8)));
typedef unsigned short u16x8 __attribute__((ext_vector_type(8)));
typedef float f32x4 __attribute__((ext_vector_type(4)));

__device__ __forceinline__ ushort f2b(float f) {
    union { float f; unsigned u; } v; v.f = f;
    unsigned u = v.u;
    return (ushort)((u + 0x7FFFu + ((u >> 16) & 1u)) >> 16);   // RNE
}
__device__ __forceinline__ float b2f(ushort u) {
    union { unsigned u; float f; } v; v.u = ((unsigned)u) << 16; return v.f;
}

// async global->LDS, 16B per lane; lds dest = wave-uniform base + lane*16
__device__ __forceinline__ void gload16(const void* g, void* l) {
    __builtin_amdgcn_global_load_lds(
        (const __attribute__((address_space(1))) unsigned int*)g,
        (__attribute__((address_space(3))) unsigned int*)l, 16, 0, 0);
}

// ---------------------------------------------------------------------------
// K1: in-degree count
__global__ void k_count_deg(const int* __restrict__ ei, int* __restrict__ deg) {
    int e = blockIdx.x * 256 + threadIdx.x;
    if (e < N_EDGES) atomicAdd(&deg[ei[N_EDGES + e]], 1);
}

// K2a: per-block inclusive scan of deg -> per-element exclusive + block sums
__global__ void k_scan_blocks(const int* __restrict__ deg, int* __restrict__ excl,
                              int* __restrict__ bsum) {
    __shared__ int sh[256];
    int t = threadIdx.x;
    int i = blockIdx.x * 256 + t;
    int v = (i < N_NODES) ? deg[i] : 0;
    sh[t] = v;
    __syncthreads();
    #pragma unroll
    for (int off = 1; off < 256; off <<= 1) {
        int add = (t >= off) ? sh[t - off] : 0;
        __syncthreads();
        sh[t] += add;
        __syncthreads();
    }
    if (i < N_NODES) excl[i] = sh[t] - v;
    if (t == 255) bsum[blockIdx.x] = sh[255];
}

// K2b: scan of block sums (single block, 512 threads >= NB)
__global__ void k_scan_sums(const int* __restrict__ bsum, int* __restrict__ boff) {
    __shared__ int sh[512];
    int t = threadIdx.x;
    int v = (t < NB) ? bsum[t] : 0;
    sh[t] = v;
    __syncthreads();
    #pragma unroll
    for (int off = 1; off < 512; off <<= 1) {
        int add = (t >= off) ? sh[t - off] : 0;
        __syncthreads();
        sh[t] += add;
        __syncthreads();
    }
    boff[t] = sh[t] - v;
}

// K2c: rowptr / inv_deg / bucket cursors
__global__ void k_finalize(const int* __restrict__ deg, const int* __restrict__ excl,
                           const int* __restrict__ boff, int* __restrict__ rowptr,
                           int* __restrict__ bcur, float* __restrict__ inv_deg) {
    int i = blockIdx.x * 256 + threadIdx.x;
    if (i < N_NODES) {
        int r = excl[i] + boff[i >> 8];
        rowptr[i] = r;
        int d = deg[i];
        inv_deg[i] = (d > 0) ? 1.0f / (float)d : 0.0f;
    }
    if (i < 512) bcur[i] = boff[i];
    if (i == 0) rowptr[N_NODES] = N_EDGES;
}

// K3a: bucket edges by dst>>8. Block-local LDS histogram -> one global atomic
// per (block,bucket) reserves a contiguous run -> clustered int2 writes.
__global__ __launch_bounds__(256) void k_bucket(const int* __restrict__ ei,
                                                int* __restrict__ bcur,
                                                int2* __restrict__ ebuf) {
    __shared__ int hist[NB];
    __shared__ int sbase[NB];
    int t = threadIdx.x;
    for (int i = t; i < NB; i += 256) hist[i] = 0;
    __syncthreads();
    int src[EPT], dst[EPT], lofs[EPT];
    int base = blockIdx.x * (256 * EPT);
    #pragma unroll
    for (int i = 0; i < EPT; ++i) {
        int e = base + i * 256 + t;
        if (e < N_EDGES) {
            src[i] = ei[e];
            dst[i] = ei[N_EDGES + e];
            lofs[i] = atomicAdd(&hist[dst[i] >> 8], 1);
        } else dst[i] = -1;
    }
    __syncthreads();
    for (int i = t; i < NB; i += 256) {
        int h = hist[i];
        sbase[i] = h ? atomicAdd(&bcur[i], h) : 0;
    }
    __syncthreads();
    #pragma unroll
    for (int i = 0; i < EPT; ++i) {
        if (dst[i] >= 0)
            ebuf[sbase[dst[i] >> 8] + lofs[i]] = make_int2(src[i], dst[i]);
    }
}

// K3b: one block per bucket; LDS cursors; csr_src writes confined to this
// bucket's contiguous ~16KB CSR window -> full-line fills, no XCD sharing.
__global__ __launch_bounds__(256) void k_place(const int* __restrict__ boff,
                                               const int2* __restrict__ ebuf,
                                               const int* __restrict__ rowptr,
                                               int* __restrict__ csr_src) {
    __shared__ int lcur[256];
    int b = blockIdx.x, t = threadIdx.x;
    int node0 = b * 256;
    if (node0 + t < N_NODES) lcur[t] = rowptr[node0 + t];
    __syncthreads();
    int e1 = boff[b + 1];
    for (int i = boff[b] + t; i < e1; i += 256) {
        int2 ed = ebuf[i];
        int pos = atomicAdd(&lcur[ed.y & 255], 1);
        csr_src[pos] = ed.x;
    }
}

// K_xcast: bf16-cast x into ABF[row][128:256]  (3.2M threads, each 4 floats)
__global__ void k_xcast(const float* __restrict__ x, ushort* __restrict__ abf) {
    int t = blockIdx.x * 256 + threadIdx.x;        // [0, 3.2M)
    float4 xv = *(const float4*)(x + (size_t)t * 4);
    int row = t >> 5;
    int colq = (t & 31) * 4;
    ushort4 o; o.x = f2b(xv.x); o.y = f2b(xv.y); o.z = f2b(xv.z); o.w = f2b(xv.w);
    *(ushort4*)(abf + (size_t)row * 256 + 128 + colq) = o;
}

// K_wbf: WBF[col][k] bf16: [w1_l | w1_r] along k; also pack w2t[col][8]
__global__ void k_wbf(const float* __restrict__ w1l, const float* __restrict__ w1r,
                      const float* __restrict__ w2l, const float* __restrict__ w2r,
                      ushort* __restrict__ wbf, float* __restrict__ w2t) {
    int i = blockIdx.x * 256 + threadIdx.x;        // [0, 65536)
    int col = i >> 8, k = i & 255;
    float v = (k < 128) ? w1l[col * 128 + k] : w1r[col * 128 + (k - 128)];
    wbf[i] = f2b(v);
    if (i < 256) {
        #pragma unroll
        for (int c = 0; c < 4; ++c) {
            w2t[i * 8 + c]     = w2l[c * HID + i];
            w2t[i * 8 + 4 + c] = w2r[c * HID + i];
        }
    }
}

// K4: mean-aggregate bf16 x-rows over in-edges. One wave per node; 16 lanes
// per edge (uniform-address index load -> HW broadcast), 2-way unrolled ->
// 8 row-gathers in flight per wave.
__global__ void k_aggregate(const int* __restrict__ rowptr, const int* __restrict__ csr_src,
                            const float* __restrict__ inv_deg, ushort* __restrict__ abf) {
    int lane = threadIdx.x & 63;
    int v = blockIdx.x * 4 + (threadIdx.x >> 6);
    if (v >= N_NODES) return;
    int r0 = rowptr[v], r1 = rowptr[v + 1];
    int q = lane >> 4, li = lane & 15;
    float a0[8], a1[8];
    #pragma unroll
    for (int j = 0; j < 8; ++j) { a0[j] = 0.f; a1[j] = 0.f; }
    int e = r0 + q;
    for (; e + 4 < r1; e += 8) {
        int s0 = csr_src[e];
        int s1 = csr_src[e + 4];
        u16x8 u0 = *(const u16x8*)(abf + (size_t)s0 * 256 + 128 + li * 8);
        u16x8 u1 = *(const u16x8*)(abf + (size_t)s1 * 256 + 128 + li * 8);
        #pragma unroll
        for (int j = 0; j < 8; ++j) { a0[j] += b2f(u0[j]); a1[j] += b2f(u1[j]); }
    }
    if (e < r1) {
        int s0 = csr_src[e];
        u16x8 u0 = *(const u16x8*)(abf + (size_t)s0 * 256 + 128 + li * 8);
        #pragma unroll
        for (int j = 0; j < 8; ++j) a0[j] += b2f(u0[j]);
    }
    #pragma unroll
    for (int j = 0; j < 8; ++j) {
        float s = a0[j] + a1[j];
        s += __shfl_xor(s, 16);
        s += __shfl_xor(s, 32);
        a0[j] = s;
    }
    if (q == 0) {
        float id = inv_deg[v];
        u16x8 o;
        #pragma unroll
        for (int j = 0; j < 8; ++j) o[j] = f2b(a0[j] * id);
        *(u16x8*)(abf + (size_t)v * 256 + li * 8) = o;
    }
}

// K5: persistent MFMA GEMM  h = relu(ABF @ WBF^T + b1)  fused with layer-2
//     projections z = h @ w2l^T, r = h @ w2r^T  (h never materialized).
// 256 blocks x 256 threads (4 waves), 1 block/CU (128KB LDS). FULL B staged
// once; one __syncthreads; each wave owns 16-row tasks.
// ROUND-9 FIX: round 8 hit the 256-VGPR cap and spilled ~300MB to scratch
// despite a ~150-reg live set -- with zero barriers the scheduler hoisted
// ds_reads across kc iterations/tasks, inflating live ranges. We now fence
// with sched_barrier(0) (COMPILE-TIME only, no wave sync) after the A-frag
// loads and after every 8-MFMA group, bounding in-flight ds_read results
// to 8 (32 VGPRs). Expected: ~170 VGPR, no spill.
__global__ __launch_bounds__(256, 1) void k_mfma(
    const ushort* __restrict__ abf, const ushort* __restrict__ wbf,
    const float* __restrict__ b1, const float* __restrict__ w2t,
    float* __restrict__ zb, float* __restrict__ rb)
{
    __shared__ ushort bufB[16 * 8 * 512];   // 128KB: sub-buffer (n*8+kc) x 1KB

    int t = threadIdx.x;
    int w = t >> 6, l = t & 63;
    int lr = l & 15, lk = l >> 4;

    // stage all of B: wave w stages sub-buffers w*32 .. w*32+31
    #pragma unroll
    for (int j = 0; j < 32; ++j) {
        int sb = w * 32 + j;
        int n = sb >> 3, kc = sb & 7;
        gload16(wbf + (size_t)(n * 16 + lr) * 256 + kc * 32 + lk * 8,
                &bufB[sb * 512]);
    }
    __syncthreads();   // only barrier in the kernel

    int wid = blockIdx.x * 4 + w;                          // [0, 1024)
    int ps = (int)(((unsigned)wid * NTASKS) >> 10);        // balanced /1024
    int pe = (int)(((unsigned)(wid + 1) * NTASKS) >> 10);

    for (int p = ps; p < pe; ++p) {
        size_t r0 = (size_t)p * 16;
        // hoist this task's 8 A-frags (16B contiguous per lane, L3-hot)
        short8v af[8];
        const ushort* a0 = abf + (r0 + lr) * 256 + lk * 8;
        #pragma unroll
        for (int kc = 0; kc < 8; ++kc)
            af[kc] = *(const short8v*)(a0 + kc * 32);
        __builtin_amdgcn_sched_barrier(0);

        f32x4 acc[16] = {};
        #pragma unroll
        for (int kc = 0; kc < 8; ++kc) {
            #pragma unroll
            for (int n = 0; n < 8; ++n) {
                short8v bf = *(const short8v*)&bufB[(n * 8 + kc) * 512 + l * 8];
                acc[n] = __builtin_amdgcn_mfma_f32_16x16x32_bf16(af[kc], bf, acc[n], 0, 0, 0);
            }
            __builtin_amdgcn_sched_barrier(0);
            #pragma unroll
            for (int n = 8; n < 16; ++n) {
                short8v bf = *(const short8v*)&bufB[(n * 8 + kc) * 512 + l * 8];
                acc[n] = __builtin_amdgcn_mfma_f32_16x16x32_bf16(af[kc], bf, acc[n], 0, 0, 0);
            }
            __builtin_amdgcn_sched_barrier(0);
        }

        // epilogue: bias+relu, layer-2 partials over this lane's 16 cols,
        // butterfly over the 16 lr-lanes, write z,r.
        float pz[4][8];
        #pragma unroll
        for (int q = 0; q < 4; ++q)
            #pragma unroll
            for (int c = 0; c < 8; ++c) pz[q][c] = 0.f;
        #pragma unroll
        for (int n = 0; n < 16; ++n) {
            int col = n * 16 + lr;
            float bias = b1[col];
            f32x4 wa = *(const f32x4*)(w2t + col * 8);
            f32x4 wb = *(const f32x4*)(w2t + col * 8 + 4);
            #pragma unroll
            for (int q = 0; q < 4; ++q) {
                float h = fmaxf(acc[n][q] + bias, 0.f);
                pz[q][0] += h * wa[0]; pz[q][1] += h * wa[1];
                pz[q][2] += h * wa[2]; pz[q][3] += h * wa[3];
                pz[q][4] += h * wb[0]; pz[q][5] += h * wb[1];
                pz[q][6] += h * wb[2]; pz[q][7] += h * wb[3];
            }
        }
        __builtin_amdgcn_sched_barrier(0);
        #pragma unroll
        for (int off = 1; off < 16; off <<= 1)
            #pragma unroll
            for (int q = 0; q < 4; ++q)
                #pragma unroll
                for (int c = 0; c < 8; ++c)
                    pz[q][c] += __shfl_xor(pz[q][c], off);
        if (lr == 0) {
            #pragma unroll
            for (int q = 0; q < 4; ++q) {
                size_t row = r0 + lk * 4 + q;   // C/D row=(l>>4)*4+reg
                if (row < N_NODES) {
                    *(float4*)(zb + row * 4) = make_float4(pz[q][0], pz[q][1], pz[q][2], pz[q][3]);
                    *(float4*)(rb + row * 4) = make_float4(pz[q][4], pz[q][5], pz[q][6], pz[q][7]);
                }
            }
        }
    }
}

// K6: aggregate z over in-edges, add bias + root term, log_softmax, write out.
__global__ void k_final(const float* __restrict__ zb, const float* __restrict__ rb,
                        const int* __restrict__ rowptr, const int* __restrict__ csr_src,
                        const float* __restrict__ inv_deg, const float* __restrict__ b2,
                        float* __restrict__ out) {
    int lane = threadIdx.x & 63;
    int v = blockIdx.x * 4 + (threadIdx.x >> 6);
    if (v >= N_NODES) return;
    int r0 = rowptr[v], r1 = rowptr[v + 1];
    float a0 = 0.f, a1 = 0.f, a2 = 0.f, a3 = 0.f;
    for (int idx = r0 + lane; idx < r1; idx += 64) {
        int s = csr_src[idx];
        float4 zv = *(const float4*)(zb + (size_t)s * 4);
        a0 += zv.x; a1 += zv.y; a2 += zv.z; a3 += zv.w;
    }
    #pragma unroll
    for (int off = 1; off < 64; off <<= 1) {
        a0 += __shfl_xor(a0, off);
        a1 += __shfl_xor(a1, off);
        a2 += __shfl_xor(a2, off);
        a3 += __shfl_xor(a3, off);
    }
    if (lane == 0) {
        float id = inv_deg[v];
        float4 rv = *(const float4*)(rb + (size_t)v * 4);
        float4 b2v = *(const float4*)b2;
        float h0 = a0 * id + b2v.x + rv.x;
        float h1 = a1 * id + b2v.y + rv.y;
        float h2 = a2 * id + b2v.z + rv.z;
        float h3 = a3 * id + b2v.w + rv.w;
        float mx = fmaxf(fmaxf(h0, h1), fmaxf(h2, h3));
        float s = expf(h0 - mx) + expf(h1 - mx) + expf(h2 - mx) + expf(h3 - mx);
        float lse = mx + logf(s);
        *(float4*)(out + (size_t)v * 4) = make_float4(h0 - lse, h1 - lse, h2 - lse, h3 - lse);
    }
}

// ---------------------------------------------------------------------------
extern "C" void kernel_launch(void* const* d_in, const int* in_sizes, int n_in,
                              void* d_out, int out_size, void* d_ws, size_t ws_size,
                              hipStream_t stream) {
    const float* x   = (const float*)d_in[0];
    const int*   ei  = (const int*)d_in[1];
    const float* w1l = (const float*)d_in[2];
    const float* w1r = (const float*)d_in[3];
    const float* b1  = (const float*)d_in[4];
    const float* w2l = (const float*)d_in[5];
    const float* w2r = (const float*)d_in[6];
    const float* b2  = (const float*)d_in[7];
    float* out = (float*)d_out;

    char* ws = (char*)d_ws;
    size_t off = 0;
    auto alloc = [&](size_t bytes) -> void* {
        void* p = ws + off;
        off = (off + bytes + 255) & ~(size_t)255;
        return p;
    };
    int* deg     = (int*)alloc(N_NODES * 4);
    int* excl    = (int*)alloc(N_NODES * 4);
    int* bsum    = (int*)alloc(512 * 4);
    int* boff    = (int*)alloc(512 * 4);
    int* rowptr  = (int*)alloc((N_NODES + 1) * 4);
    int* bcur    = (int*)alloc(512 * 4);
    int* csr_src = (int*)alloc((size_t)N_EDGES * 4);
    int2* ebuf   = (int2*)alloc((size_t)N_EDGES * 8);
    float* inv_deg = (float*)alloc(N_NODES * 4);
    ushort* abf  = (ushort*)alloc((size_t)N_ROWS_PAD * 256 * 2);  // [agg | x] bf16
    ushort* wbf  = (ushort*)alloc((size_t)256 * 256 * 2);         // [w1l | w1r] bf16
    float* w2t   = (float*)alloc(256 * 8 * 4);                    // [col][z0..3 r0..3]
    float* zb    = (float*)alloc((size_t)N_NODES * 4 * 4);
    float* rb    = (float*)alloc((size_t)N_NODES * 4 * 4);

    hipMemsetAsync(deg, 0, N_NODES * 4, stream);

    const int EB = (N_EDGES + 255) / 256;   // 6250
    k_count_deg<<<EB, 256, 0, stream>>>(ei, deg);
    k_scan_blocks<<<NB, 256, 0, stream>>>(deg, excl, bsum);
    k_scan_sums<<<1, 512, 0, stream>>>(bsum, boff);
    k_finalize<<<NB, 256, 0, stream>>>(deg, excl, boff, rowptr, bcur, inv_deg);
    k_bucket<<<(N_EDGES + 256 * EPT - 1) / (256 * EPT), 256, 0, stream>>>(ei, bcur, ebuf);
    k_place<<<NB, 256, 0, stream>>>(boff, ebuf, rowptr, csr_src);
    k_wbf<<<256, 256, 0, stream>>>(w1l, w1r, w2l, w2r, wbf, w2t);
    k_xcast<<<12500, 256, 0, stream>>>(x, abf);
    k_aggregate<<<(N_NODES + 3) / 4, 256, 0, stream>>>(rowptr, csr_src, inv_deg, abf);
    k_mfma<<<GEMM_BLOCKS, 256, 0, stream>>>(abf, wbf, b1, w2t, zb, rb);
    k_final<<<(N_NODES + 3) / 4, 256, 0, stream>>>(zb, rb, rowptr, csr_src, inv_deg, b2, out);
}

// Round 10
// 208.867 us; speedup vs baseline: 2.5779x; 1.2631x over previous
//
#include <hip/hip_runtime.h>

#define N_NODES 100000
#define N_ROWS_PAD 100032   // multiple of 64 for the MFMA kernel
#define N_EDGES 1600000
#define F_IN    128
#define HID     256
#define C_OUT   4

#define NB 391        // ceil(N_NODES/256) buckets
#define EPT 16        // edges per thread in bucket kernels

#define GEMM_BLOCKS 256
#define NTASKS 6252   // N_ROWS_PAD / 16

typedef short short8v __attribute__((ext_vector_type(8)));
typedef unsigned short u16x8 __attribute__((ext_vector_type(8)));
typedef float f32x4 __attribute__((ext_vector_type(4)));

__device__ __forceinline__ ushort f2b(float f) {
    union { float f; unsigned u; } v; v.f = f;
    unsigned u = v.u;
    return (ushort)((u + 0x7FFFu + ((u >> 16) & 1u)) >> 16);   // RNE
}
__device__ __forceinline__ float b2f(ushort u) {
    union { unsigned u; float f; } v; v.u = ((unsigned)u) << 16; return v.f;
}

// async global->LDS, 16B per lane; lds dest = wave-uniform base + lane*16
__device__ __forceinline__ void gload16(const void* g, void* l) {
    __builtin_amdgcn_global_load_lds(
        (const __attribute__((address_space(1))) unsigned int*)g,
        (__attribute__((address_space(3))) unsigned int*)l, 16, 0, 0);
}

// ---------------------------------------------------------------------------
// K1: count edges per 256-node BUCKET (LDS hist -> 391 global counters).
// Replaces per-node k_count_deg (1.6M atomics on 100k random lines -> 50MB
// of cross-XCD writeback, 65us). Per-node degrees are recovered bucket-
// locally in k_place with LDS-only atomics.
__global__ __launch_bounds__(256) void k_bcount(const int* __restrict__ ei,
                                                int* __restrict__ bktcnt) {
    __shared__ int hist[NB];
    int t = threadIdx.x;
    for (int i = t; i < NB; i += 256) hist[i] = 0;
    __syncthreads();
    int base = blockIdx.x * (256 * EPT);
    #pragma unroll
    for (int i = 0; i < EPT; ++i) {
        int e = base + i * 256 + t;
        if (e < N_EDGES) atomicAdd(&hist[ei[N_EDGES + e] >> 8], 1);
    }
    __syncthreads();
    for (int i = t; i < NB; i += 256)
        if (hist[i]) atomicAdd(&bktcnt[i], hist[i]);
}

// K2: scan 391 bucket counts -> boff (bucket CSR offsets) + bcur copy.
__global__ void k_bscan(const int* __restrict__ bktcnt, int* __restrict__ boff,
                        int* __restrict__ bcur) {
    __shared__ int sh[512];
    int t = threadIdx.x;
    int v = (t < NB) ? bktcnt[t] : 0;
    sh[t] = v;
    __syncthreads();
    #pragma unroll
    for (int off = 1; off < 512; off <<= 1) {
        int add = (t >= off) ? sh[t - off] : 0;
        __syncthreads();
        sh[t] += add;
        __syncthreads();
    }
    int excl = sh[t] - v;
    boff[t] = excl;           // boff[NB] = N_EDGES lands naturally at t==NB
    bcur[t] = excl;
}

// K3a: bucket edges by dst>>8. Block-local LDS histogram -> one global atomic
// per (block,bucket) reserves a contiguous run -> clustered int2 writes.
__global__ __launch_bounds__(256) void k_bucket(const int* __restrict__ ei,
                                                int* __restrict__ bcur,
                                                int2* __restrict__ ebuf) {
    __shared__ int hist[NB];
    __shared__ int sbase[NB];
    int t = threadIdx.x;
    for (int i = t; i < NB; i += 256) hist[i] = 0;
    __syncthreads();
    int src[EPT], dst[EPT], lofs[EPT];
    int base = blockIdx.x * (256 * EPT);
    #pragma unroll
    for (int i = 0; i < EPT; ++i) {
        int e = base + i * 256 + t;
        if (e < N_EDGES) {
            src[i] = ei[e];
            dst[i] = ei[N_EDGES + e];
            lofs[i] = atomicAdd(&hist[dst[i] >> 8], 1);
        } else dst[i] = -1;
    }
    __syncthreads();
    for (int i = t; i < NB; i += 256) {
        int h = hist[i];
        sbase[i] = h ? atomicAdd(&bcur[i], h) : 0;
    }
    __syncthreads();
    #pragma unroll
    for (int i = 0; i < EPT; ++i) {
        if (dst[i] >= 0)
            ebuf[sbase[dst[i] >> 8] + lofs[i]] = make_int2(src[i], dst[i]);
    }
}

// K3b: one block per bucket. Pass 1: per-node degree in LDS + in-block scan
// -> rowptr/inv_deg (no global atomics at all). Pass 2: place csr_src via
// LDS cursors; writes confined to this bucket's contiguous CSR window.
__global__ __launch_bounds__(256) void k_place(const int* __restrict__ boff,
                                               const int2* __restrict__ ebuf,
                                               int* __restrict__ rowptr,
                                               float* __restrict__ inv_deg,
                                               int* __restrict__ csr_src) {
    __shared__ int ldeg[256];
    __shared__ int sh[256];
    __shared__ int lcur[256];
    int b = blockIdx.x, t = threadIdx.x;
    ldeg[t] = 0;
    __syncthreads();
    int e0 = boff[b], e1 = boff[b + 1];
    for (int i = e0 + t; i < e1; i += 256)
        atomicAdd(&ldeg[ebuf[i].y & 255], 1);
    __syncthreads();
    int v = ldeg[t];
    sh[t] = v;
    __syncthreads();
    #pragma unroll
    for (int off = 1; off < 256; off <<= 1) {
        int add = (t >= off) ? sh[t - off] : 0;
        __syncthreads();
        sh[t] += add;
        __syncthreads();
    }
    int start = e0 + sh[t] - v;
    int node = b * 256 + t;
    if (node < N_NODES) {
        rowptr[node] = start;
        inv_deg[node] = (v > 0) ? 1.0f / (float)v : 0.0f;
    }
    if (b == 0 && t == 0) rowptr[N_NODES] = N_EDGES;
    lcur[t] = start;
    __syncthreads();
    for (int i = e0 + t; i < e1; i += 256) {
        int2 ed = ebuf[i];
        int pos = atomicAdd(&lcur[ed.y & 255], 1);
        csr_src[pos] = ed.x;
    }
}

// K_xcast: bf16-cast x into ABF[row][128:256]  (3.2M threads, each 4 floats)
__global__ void k_xcast(const float* __restrict__ x, ushort* __restrict__ abf) {
    int t = blockIdx.x * 256 + threadIdx.x;        // [0, 3.2M)
    float4 xv = *(const float4*)(x + (size_t)t * 4);
    int row = t >> 5;
    int colq = (t & 31) * 4;
    ushort4 o; o.x = f2b(xv.x); o.y = f2b(xv.y); o.z = f2b(xv.z); o.w = f2b(xv.w);
    *(ushort4*)(abf + (size_t)row * 256 + 128 + colq) = o;
}

// K_wbf: WBF[col][k] bf16: [w1_l | w1_r] along k; also pack w2t[col][8]
__global__ void k_wbf(const float* __restrict__ w1l, const float* __restrict__ w1r,
                      const float* __restrict__ w2l, const float* __restrict__ w2r,
                      ushort* __restrict__ wbf, float* __restrict__ w2t) {
    int i = blockIdx.x * 256 + threadIdx.x;        // [0, 65536)
    int col = i >> 8, k = i & 255;
    float v = (k < 128) ? w1l[col * 128 + k] : w1r[col * 128 + (k - 128)];
    wbf[i] = f2b(v);
    if (i < 256) {
        #pragma unroll
        for (int c = 0; c < 4; ++c) {
            w2t[i * 8 + c]     = w2l[c * HID + i];
            w2t[i * 8 + 4 + c] = w2r[c * HID + i];
        }
    }
}

// K4: mean-aggregate bf16 x-rows over in-edges. One wave per node; 16 lanes
// per edge (uniform-address index load -> HW broadcast), 2-way unrolled ->
// 8 row-gathers in flight per wave.
__global__ void k_aggregate(const int* __restrict__ rowptr, const int* __restrict__ csr_src,
                            const float* __restrict__ inv_deg, ushort* __restrict__ abf) {
    int lane = threadIdx.x & 63;
    int v = blockIdx.x * 4 + (threadIdx.x >> 6);
    if (v >= N_NODES) return;
    int r0 = rowptr[v], r1 = rowptr[v + 1];
    int q = lane >> 4, li = lane & 15;
    float a0[8], a1[8];
    #pragma unroll
    for (int j = 0; j < 8; ++j) { a0[j] = 0.f; a1[j] = 0.f; }
    int e = r0 + q;
    for (; e + 4 < r1; e += 8) {
        int s0 = csr_src[e];
        int s1 = csr_src[e + 4];
        u16x8 u0 = *(const u16x8*)(abf + (size_t)s0 * 256 + 128 + li * 8);
        u16x8 u1 = *(const u16x8*)(abf + (size_t)s1 * 256 + 128 + li * 8);
        #pragma unroll
        for (int j = 0; j < 8; ++j) { a0[j] += b2f(u0[j]); a1[j] += b2f(u1[j]); }
    }
    if (e < r1) {
        int s0 = csr_src[e];
        u16x8 u0 = *(const u16x8*)(abf + (size_t)s0 * 256 + 128 + li * 8);
        #pragma unroll
        for (int j = 0; j < 8; ++j) a0[j] += b2f(u0[j]);
    }
    #pragma unroll
    for (int j = 0; j < 8; ++j) {
        float s = a0[j] + a1[j];
        s += __shfl_xor(s, 16);
        s += __shfl_xor(s, 32);
        a0[j] = s;
    }
    if (q == 0) {
        float id = inv_deg[v];
        u16x8 o;
        #pragma unroll
        for (int j = 0; j < 8; ++j) o[j] = f2b(a0[j] * id);
        *(u16x8*)(abf + (size_t)v * 256 + li * 8) = o;
    }
}

// K5: persistent MFMA GEMM  h = relu(ABF @ WBF^T + b1)  fused with layer-2
//     projections z = h @ w2l^T, r = h @ w2r^T  (h never materialized).
// 256 blocks x 256 threads (4 waves), 1 block/CU (128KB LDS). FULL B staged
// once; one __syncthreads; each wave owns 16-row tasks. sched_barrier(0)
// fences (round 9) bound live ranges -> no spill (round 8 spilled 300MB).
__global__ __launch_bounds__(256, 1) void k_mfma(
    const ushort* __restrict__ abf, const ushort* __restrict__ wbf,
    const float* __restrict__ b1, const float* __restrict__ w2t,
    float* __restrict__ zb, float* __restrict__ rb)
{
    __shared__ ushort bufB[16 * 8 * 512];   // 128KB: sub-buffer (n*8+kc) x 1KB

    int t = threadIdx.x;
    int w = t >> 6, l = t & 63;
    int lr = l & 15, lk = l >> 4;

    // stage all of B: wave w stages sub-buffers w*32 .. w*32+31
    #pragma unroll
    for (int j = 0; j < 32; ++j) {
        int sb = w * 32 + j;
        int n = sb >> 3, kc = sb & 7;
        gload16(wbf + (size_t)(n * 16 + lr) * 256 + kc * 32 + lk * 8,
                &bufB[sb * 512]);
    }
    __syncthreads();   // only barrier in the kernel

    int wid = blockIdx.x * 4 + w;                          // [0, 1024)
    int ps = (int)(((unsigned)wid * NTASKS) >> 10);        // balanced /1024
    int pe = (int)(((unsigned)(wid + 1) * NTASKS) >> 10);

    for (int p = ps; p < pe; ++p) {
        size_t r0 = (size_t)p * 16;
        // hoist this task's 8 A-frags (16B contiguous per lane, L3-hot)
        short8v af[8];
        const ushort* a0 = abf + (r0 + lr) * 256 + lk * 8;
        #pragma unroll
        for (int kc = 0; kc < 8; ++kc)
            af[kc] = *(const short8v*)(a0 + kc * 32);
        __builtin_amdgcn_sched_barrier(0);

        f32x4 acc[16] = {};
        #pragma unroll
        for (int kc = 0; kc < 8; ++kc) {
            #pragma unroll
            for (int n = 0; n < 8; ++n) {
                short8v bf = *(const short8v*)&bufB[(n * 8 + kc) * 512 + l * 8];
                acc[n] = __builtin_amdgcn_mfma_f32_16x16x32_bf16(af[kc], bf, acc[n], 0, 0, 0);
            }
            __builtin_amdgcn_sched_barrier(0);
            #pragma unroll
            for (int n = 8; n < 16; ++n) {
                short8v bf = *(const short8v*)&bufB[(n * 8 + kc) * 512 + l * 8];
                acc[n] = __builtin_amdgcn_mfma_f32_16x16x32_bf16(af[kc], bf, acc[n], 0, 0, 0);
            }
            __builtin_amdgcn_sched_barrier(0);
        }

        // epilogue: bias+relu, layer-2 partials over this lane's 16 cols,
        // butterfly over the 16 lr-lanes, write z,r.
        float pz[4][8];
        #pragma unroll
        for (int q = 0; q < 4; ++q)
            #pragma unroll
            for (int c = 0; c < 8; ++c) pz[q][c] = 0.f;
        #pragma unroll
        for (int n = 0; n < 16; ++n) {
            int col = n * 16 + lr;
            float bias = b1[col];
            f32x4 wa = *(const f32x4*)(w2t + col * 8);
            f32x4 wb = *(const f32x4*)(w2t + col * 8 + 4);
            #pragma unroll
            for (int q = 0; q < 4; ++q) {
                float h = fmaxf(acc[n][q] + bias, 0.f);
                pz[q][0] += h * wa[0]; pz[q][1] += h * wa[1];
                pz[q][2] += h * wa[2]; pz[q][3] += h * wa[3];
                pz[q][4] += h * wb[0]; pz[q][5] += h * wb[1];
                pz[q][6] += h * wb[2]; pz[q][7] += h * wb[3];
            }
        }
        __builtin_amdgcn_sched_barrier(0);
        #pragma unroll
        for (int off = 1; off < 16; off <<= 1)
            #pragma unroll
            for (int q = 0; q < 4; ++q)
                #pragma unroll
                for (int c = 0; c < 8; ++c)
                    pz[q][c] += __shfl_xor(pz[q][c], off);
        if (lr == 0) {
            #pragma unroll
            for (int q = 0; q < 4; ++q) {
                size_t row = r0 + lk * 4 + q;   // C/D row=(l>>4)*4+reg
                if (row < N_NODES) {
                    *(float4*)(zb + row * 4) = make_float4(pz[q][0], pz[q][1], pz[q][2], pz[q][3]);
                    *(float4*)(rb + row * 4) = make_float4(pz[q][4], pz[q][5], pz[q][6], pz[q][7]);
                }
            }
        }
    }
}

// K6: aggregate z over in-edges, add bias + root term, log_softmax, write out.
__global__ void k_final(const float* __restrict__ zb, const float* __restrict__ rb,
                        const int* __restrict__ rowptr, const int* __restrict__ csr_src,
                        const float* __restrict__ inv_deg, const float* __restrict__ b2,
                        float* __restrict__ out) {
    int lane = threadIdx.x & 63;
    int v = blockIdx.x * 4 + (threadIdx.x >> 6);
    if (v >= N_NODES) return;
    int r0 = rowptr[v], r1 = rowptr[v + 1];
    float a0 = 0.f, a1 = 0.f, a2 = 0.f, a3 = 0.f;
    for (int idx = r0 + lane; idx < r1; idx += 64) {
        int s = csr_src[idx];
        float4 zv = *(const float4*)(zb + (size_t)s * 4);
        a0 += zv.x; a1 += zv.y; a2 += zv.z; a3 += zv.w;
    }
    #pragma unroll
    for (int off = 1; off < 64; off <<= 1) {
        a0 += __shfl_xor(a0, off);
        a1 += __shfl_xor(a1, off);
        a2 += __shfl_xor(a2, off);
        a3 += __shfl_xor(a3, off);
    }
    if (lane == 0) {
        float id = inv_deg[v];
        float4 rv = *(const float4*)(rb + (size_t)v * 4);
        float4 b2v = *(const float4*)b2;
        float h0 = a0 * id + b2v.x + rv.x;
        float h1 = a1 * id + b2v.y + rv.y;
        float h2 = a2 * id + b2v.z + rv.z;
        float h3 = a3 * id + b2v.w + rv.w;
        float mx = fmaxf(fmaxf(h0, h1), fmaxf(h2, h3));
        float s = expf(h0 - mx) + expf(h1 - mx) + expf(h2 - mx) + expf(h3 - mx);
        float lse = mx + logf(s);
        *(float4*)(out + (size_t)v * 4) = make_float4(h0 - lse, h1 - lse, h2 - lse, h3 - lse);
    }
}

// ---------------------------------------------------------------------------
extern "C" void kernel_launch(void* const* d_in, const int* in_sizes, int n_in,
                              void* d_out, int out_size, void* d_ws, size_t ws_size,
                              hipStream_t stream) {
    const float* x   = (const float*)d_in[0];
    const int*   ei  = (const int*)d_in[1];
    const float* w1l = (const float*)d_in[2];
    const float* w1r = (const float*)d_in[3];
    const float* b1  = (const float*)d_in[4];
    const float* w2l = (const float*)d_in[5];
    const float* w2r = (const float*)d_in[6];
    const float* b2  = (const float*)d_in[7];
    float* out = (float*)d_out;

    char* ws = (char*)d_ws;
    size_t off = 0;
    auto alloc = [&](size_t bytes) -> void* {
        void* p = ws + off;
        off = (off + bytes + 255) & ~(size_t)255;
        return p;
    };
    int* bktcnt  = (int*)alloc(512 * 4);
    int* boff    = (int*)alloc(512 * 4);
    int* bcur    = (int*)alloc(512 * 4);
    int* rowptr  = (int*)alloc((N_NODES + 1) * 4);
    int* csr_src = (int*)alloc((size_t)N_EDGES * 4);
    int2* ebuf   = (int2*)alloc((size_t)N_EDGES * 8);
    float* inv_deg = (float*)alloc(N_NODES * 4);
    ushort* abf  = (ushort*)alloc((size_t)N_ROWS_PAD * 256 * 2);  // [agg | x] bf16
    ushort* wbf  = (ushort*)alloc((size_t)256 * 256 * 2);         // [w1l | w1r] bf16
    float* w2t   = (float*)alloc(256 * 8 * 4);                    // [col][z0..3 r0..3]
    float* zb    = (float*)alloc((size_t)N_NODES * 4 * 4);
    float* rb    = (float*)alloc((size_t)N_NODES * 4 * 4);

    hipMemsetAsync(bktcnt, 0, 512 * 4, stream);

    const int BKB = (N_EDGES + 256 * EPT - 1) / (256 * EPT);   // 391
    k_bcount<<<BKB, 256, 0, stream>>>(ei, bktcnt);
    k_bscan<<<1, 512, 0, stream>>>(bktcnt, boff, bcur);
    k_bucket<<<BKB, 256, 0, stream>>>(ei, bcur, ebuf);
    k_place<<<NB, 256, 0, stream>>>(boff, ebuf, rowptr, inv_deg, csr_src);
    k_wbf<<<256, 256, 0, stream>>>(w1l, w1r, w2l, w2r, wbf, w2t);
    k_xcast<<<12500, 256, 0, stream>>>(x, abf);
    k_aggregate<<<(N_NODES + 3) / 4, 256, 0, stream>>>(rowptr, csr_src, inv_deg, abf);
    k_mfma<<<GEMM_BLOCKS, 256, 0, stream>>>(abf, wbf, b1, w2t, zb, rb);
    k_final<<<(N_NODES + 3) / 4, 256, 0, stream>>>(zb, rb, rowptr, csr_src, inv_deg, b2, out);
}